// Round 1
// baseline (2343.540 us; speedup 1.0000x reference)
//
#include <hip/hip_runtime.h>

// Problem constants (fixed by reference):
// B=4, N=2048, Din=256, Dout=64, Hh=8
#define B_  4
#define N_  2048
#define DIN 256
#define DOUT 64
#define HH  8

// ---------------------------------------------------------------------------
// Kernel 1: Wh[b,h,n,e] = sum_d H[b,n,d] * W[h,d,e]; f2[b,h,n] = Wh . a2[h]
// block = 256 threads = 4 waves; each wave handles one row r=(b,h,n), lane=e.
// ---------------------------------------------------------------------------
__global__ __launch_bounds__(256) void k_wh_f2(
    const float* __restrict__ H, const float* __restrict__ W,
    const float* __restrict__ a, float* __restrict__ Wh,
    float* __restrict__ f2) {
  __shared__ __align__(16) float hs[4][DIN];
  const int w = threadIdx.x >> 6, lane = threadIdx.x & 63;
  const int r = blockIdx.x * 4 + w;       // r in [0, B*HH*N)
  const int b = r >> 14;                  // / (HH*N)
  const int h = (r >> 11) & 7;
  const int n = r & 2047;

  // stage H row (256 f32) into LDS, coalesced float4
  const float* Hrow = H + ((size_t)(b * N_ + n)) * DIN;
  float4 hv = *reinterpret_cast<const float4*>(Hrow + lane * 4);
  hs[w][lane * 4 + 0] = hv.x;
  hs[w][lane * 4 + 1] = hv.y;
  hs[w][lane * 4 + 2] = hv.z;
  hs[w][lane * 4 + 3] = hv.w;
  __syncthreads();

  const float* Wp = W + (size_t)h * DIN * DOUT + lane;
  float acc = 0.f;
#pragma unroll 8
  for (int d = 0; d < DIN; ++d) acc += hs[w][d] * Wp[(size_t)d * DOUT];

  Wh[(size_t)r * DOUT + lane] = acc;

  // f2 = sum_e Wh*a2[h,e]
  float r2 = acc * a[h * (2 * DOUT) + DOUT + lane];
#pragma unroll
  for (int off = 32; off > 0; off >>= 1) r2 += __shfl_xor(r2, off, 64);
  if (lane == 0) f2[r] = r2;
}

// ---------------------------------------------------------------------------
// Kernel 1b: per (b,h): mx = max_m f2; Ef2[m] = exp(f2[m]-mx)
// 32 blocks x 256 threads
// ---------------------------------------------------------------------------
__global__ __launch_bounds__(256) void k_ef2(const float* __restrict__ f2,
                                             float* __restrict__ Ef2) {
  __shared__ float red[256];
  const int bh = blockIdx.x;
  const int t = threadIdx.x;
  const float* src = f2 + (size_t)bh * N_;
  float v[8];
  float mx = -1e30f;
#pragma unroll
  for (int j = 0; j < 8; ++j) {
    v[j] = src[t + j * 256];
    mx = fmaxf(mx, v[j]);
  }
  red[t] = mx;
  __syncthreads();
  for (int s = 128; s > 0; s >>= 1) {
    if (t < s) red[t] = fmaxf(red[t], red[t + s]);
    __syncthreads();
  }
  mx = red[0];
  float* dst = Ef2 + (size_t)bh * N_;
#pragma unroll
  for (int j = 0; j < 8; ++j) dst[t + j * 256] = __expf(v[j] - mx);
}

// ---------------------------------------------------------------------------
// Kernel 2: per block = (b, tile of 16 rows n).
//  Phase A: pack adj bits for the 16 rows into LDS (ballot).
//  For each head h:
//    load Ef2[b,h,:] into LDS
//    each wave processes 4 rows: S, alpha (write + LDS stage), PV, out0.
// ---------------------------------------------------------------------------
__global__ __launch_bounds__(256) void k_main(
    const int* __restrict__ adj, const float* __restrict__ Ef2,
    const float* __restrict__ Wh, float* __restrict__ out0,
    float* __restrict__ alpha) {
  __shared__ __align__(16) float ef2s[N_];                 // 8 KB
  __shared__ unsigned long long bits[16][N_ / 64];         // 4 KB
  __shared__ __align__(16) float alph[4][N_];              // 32 KB

  const int w = threadIdx.x >> 6, lane = threadIdx.x & 63;
  const int b = blockIdx.x >> 7;
  const int n0 = (blockIdx.x & 127) * 16;

  // --- Phase A: pack adjacency bits ---
  for (int nl = 0; nl < 16; ++nl) {
    const int* arow = adj + ((size_t)(b * N_ + n0 + nl)) * N_;
#pragma unroll
    for (int i = 0; i < 8; ++i) {
      int m = w * 512 + i * 64 + lane;
      unsigned long long msk = __ballot(arow[m] != 0);
      if (lane == 0) bits[nl][w * 8 + i] = msk;
    }
  }
  __syncthreads();

  for (int h = 0; h < HH; ++h) {
    const size_t bh = (size_t)(b * HH + h);
    __syncthreads();  // protect ef2s from previous head's readers
    {
      const float* ef2g = Ef2 + bh * N_;
#pragma unroll
      for (int j = 0; j < 8; ++j)
        ef2s[threadIdx.x + j * 256] = ef2g[threadIdx.x + j * 256];
    }
    __syncthreads();

    for (int rr = 0; rr < 4; ++rr) {
      const int nl = rr * 4 + w;
      const int n = n0 + nl;

      // --- S = sum over neighbors of Ef2 ---
      float s = 0.f;
#pragma unroll 4
      for (int k = 0; k < N_ / 64; ++k) {
        unsigned long long word = bits[nl][k];
        if ((word >> lane) & 1ull) s += ef2s[k * 64 + lane];
      }
#pragma unroll
      for (int off = 32; off > 0; off >>= 1) s += __shfl_xor(s, off, 64);

      const bool empty = (s == 0.f);
      const float inv = empty ? (1.f / (float)N_) : 1.f / s;

      // --- alpha: write to global + stage in LDS ---
      float* aLDS = alph[w];
      float* ag = alpha + (bh * N_ + n) * (size_t)N_;
#pragma unroll 4
      for (int k = 0; k < N_ / 64; ++k) {
        unsigned long long word = bits[nl][k];
        float av;
        if (empty)
          av = 1.f / (float)N_;
        else
          av = ((word >> lane) & 1ull) ? ef2s[k * 64 + lane] * inv : 0.f;
        aLDS[k * 64 + lane] = av;
        ag[k * 64 + lane] = av;
      }
      __syncthreads();  // make own-wave LDS writes visible across lanes

      // --- PV: h_prime[e] = sum_m alpha[m] * Wh[b,h,m,e], lane = e ---
      const float* wrow = Wh + bh * ((size_t)N_ * DOUT) + lane;
      float acc = 0.f;
#pragma unroll 2
      for (int m = 0; m < N_; m += 4) {
        float4 a4 = *reinterpret_cast<const float4*>(&aLDS[m]);
        acc += a4.x * wrow[(size_t)(m + 0) * DOUT];
        acc += a4.y * wrow[(size_t)(m + 1) * DOUT];
        acc += a4.z * wrow[(size_t)(m + 2) * DOUT];
        acc += a4.w * wrow[(size_t)(m + 3) * DOUT];
      }
      out0[((size_t)(b * N_ + n)) * (HH * DOUT) + h * DOUT + lane] =
          fmaxf(acc, 0.f);
    }
  }
}

// ---------------------------------------------------------------------------
extern "C" void kernel_launch(void* const* d_in, const int* in_sizes, int n_in,
                              void* d_out, int out_size, void* d_ws,
                              size_t ws_size, hipStream_t stream) {
  const float* H = (const float*)d_in[0];   // (4,2048,256)
  const int* adj = (const int*)d_in[1];     // (4,2048,2048)
  const float* W = (const float*)d_in[2];   // (8,256,64)
  const float* a = (const float*)d_in[3];   // (8,128)

  float* out = (float*)d_out;
  float* out0 = out;                                 // (4,2048,512)
  float* alpha = out + (size_t)B_ * N_ * HH * DOUT;  // (4,8,2048,2048)

  // workspace layout
  float* Wh = (float*)d_ws;                       // B*HH*N*DOUT = 4.19M f32
  float* f2 = Wh + (size_t)B_ * HH * N_ * DOUT;   // 65536 f32
  float* Ef2 = f2 + (size_t)B_ * HH * N_;         // 65536 f32

  k_wh_f2<<<(B_ * HH * N_) / 4, 256, 0, stream>>>(H, W, a, Wh, f2);
  k_ef2<<<B_ * HH, 256, 0, stream>>>(f2, Ef2);
  k_main<<<B_ * (N_ / 16), 256, 0, stream>>>(adj, Ef2, Wh, out0, alpha);
}

// Round 2
// 715.246 us; speedup vs baseline: 3.2766x; 3.2766x over previous
//
#include <hip/hip_runtime.h>

#define B_  4
#define N_  2048
#define DIN 256
#define DOUT 64
#define HH  8
#define MT  128   // m-tile staged in LDS for PV

// ---------------------------------------------------------------------------
// Kernel 1: Wh[b,h,n,e] = sum_d H[b,n,d] * W[h,d,e]; f2[b,h,n] = Wh . a2[h]
// block = (bh, 16-row n-tile); 4 waves, each wave 4 rows.
// Lane split: q = lane>>4 (d sub-index), g = lane&15 (e quad).
// ---------------------------------------------------------------------------
__global__ __launch_bounds__(256) void k_wh_f2(
    const float* __restrict__ H, const float* __restrict__ W,
    const float* __restrict__ a, float* __restrict__ Wh,
    float* __restrict__ f2) {
  __shared__ __align__(16) float hs[16][DIN];  // 16 KB
  const int t = threadIdx.x, w = t >> 6, lane = t & 63;
  const int q = lane >> 4, g = lane & 15;
  const int bh = blockIdx.x >> 7;       // 32 bh values
  const int tile = blockIdx.x & 127;
  const int b = bh >> 3, h = bh & 7;
  const int n0 = tile * 16;

  // stage 16 H rows (16 KB), coalesced float4
  const float* Hbase = H + ((size_t)(b * N_ + n0)) * DIN;
#pragma unroll
  for (int j = 0; j < 4; ++j) {
    int idx = j * 256 + t;          // 0..1023 float4s
    int row = idx >> 6, c4 = idx & 63;
    float4 v = *reinterpret_cast<const float4*>(Hbase + (size_t)row * DIN + c4 * 4);
    *reinterpret_cast<float4*>(&hs[row][c4 * 4]) = v;
  }
  __syncthreads();

  const float* Wp = W + (size_t)h * DIN * DOUT;
  const float4 a2v = *reinterpret_cast<const float4*>(a + h * (2 * DOUT) + DOUT + 4 * g);

  float4 acc[4];
#pragma unroll
  for (int r = 0; r < 4; ++r) acc[r] = make_float4(0.f, 0.f, 0.f, 0.f);

#pragma unroll 4
  for (int d0 = 0; d0 < DIN; d0 += 4) {
    const float4 wv = *reinterpret_cast<const float4*>(Wp + (size_t)(d0 + q) * DOUT + 4 * g);
#pragma unroll
    for (int r = 0; r < 4; ++r) {
      const float hv = hs[w * 4 + r][d0 + q];
      acc[r].x += hv * wv.x; acc[r].y += hv * wv.y;
      acc[r].z += hv * wv.z; acc[r].w += hv * wv.w;
    }
  }

#pragma unroll
  for (int r = 0; r < 4; ++r) {
    // reduce over q (4 partial groups at lane distance 16, 32)
    float4 v = acc[r];
#pragma unroll
    for (int off = 16; off <= 32; off <<= 1) {
      v.x += __shfl_xor(v.x, off, 64);
      v.y += __shfl_xor(v.y, off, 64);
      v.z += __shfl_xor(v.z, off, 64);
      v.w += __shfl_xor(v.w, off, 64);
    }
    const int n = n0 + w * 4 + r;
    if (q == 0)
      *reinterpret_cast<float4*>(Wh + ((size_t)bh * N_ + n) * DOUT + 4 * g) = v;
    // f2 = Wh . a2
    float fr = v.x * a2v.x + v.y * a2v.y + v.z * a2v.z + v.w * a2v.w;
    fr += __shfl_xor(fr, 1, 64);
    fr += __shfl_xor(fr, 2, 64);
    fr += __shfl_xor(fr, 4, 64);
    fr += __shfl_xor(fr, 8, 64);
    if (lane == 0) f2[(size_t)bh * N_ + n] = fr;
  }
}

// ---------------------------------------------------------------------------
// Kernel 1b: per (b,h): mx = max_m f2; Ef2[m] = exp(f2[m]-mx)
// ---------------------------------------------------------------------------
__global__ __launch_bounds__(256) void k_ef2(const float* __restrict__ f2,
                                             float* __restrict__ Ef2) {
  __shared__ float red[256];
  const int bh = blockIdx.x;
  const int t = threadIdx.x;
  const float* src = f2 + (size_t)bh * N_;
  float v[8];
  float mx = -1e30f;
#pragma unroll
  for (int j = 0; j < 8; ++j) {
    v[j] = src[t + j * 256];
    mx = fmaxf(mx, v[j]);
  }
  red[t] = mx;
  __syncthreads();
  for (int s = 128; s > 0; s >>= 1) {
    if (t < s) red[t] = fmaxf(red[t], red[t + s]);
    __syncthreads();
  }
  mx = red[0];
  float* dst = Ef2 + (size_t)bh * N_;
#pragma unroll
  for (int j = 0; j < 8; ++j) dst[t + j * 256] = __expf(v[j] - mx);
}

// ---------------------------------------------------------------------------
// Kernel 2: per block = (b, 16-row n-tile).
//  Phase A: pack adj bits into LDS (reused by all 8 heads).
//  Per head: ef2s -> LDS; per wave (4 rows): S + alpha global write;
//  PV with Wh m-tiles staged in LDS (reused by all 16 rows).
// ---------------------------------------------------------------------------
__global__ __launch_bounds__(256) void k_main(
    const int* __restrict__ adj, const float* __restrict__ Ef2,
    const float* __restrict__ Wh, float* __restrict__ out0,
    float* __restrict__ alpha) {
  __shared__ float ef2s[N_];                        // 8 KB
  __shared__ unsigned long long bits[16][N_ / 64];  // 4 KB
  __shared__ __align__(16) float whs[MT][DOUT];     // 32 KB

  const int t = threadIdx.x, w = t >> 6, lane = t & 63;
  const int q = lane >> 4, g = lane & 15;
  const int b = blockIdx.x >> 7;
  const int n0 = (blockIdx.x & 127) * 16;
  const float invN = 1.f / (float)N_;

  // --- Phase A: pack adjacency bits (wave w covers m in [512w, 512w+512)) ---
  for (int nl = 0; nl < 16; ++nl) {
    const int* arow = adj + ((size_t)(b * N_ + n0 + nl)) * N_;
#pragma unroll
    for (int i = 0; i < 8; ++i) {
      int m = w * 512 + i * 64 + lane;
      unsigned long long msk = __ballot(arow[m] != 0);
      if (lane == 0) bits[nl][w * 8 + i] = msk;
    }
  }
  __syncthreads();

  for (int h = 0; h < HH; ++h) {
    const size_t bh = (size_t)(b * HH + h);
    __syncthreads();  // previous head's readers of ef2s are done
    {
      const float* ef2g = Ef2 + bh * N_;
#pragma unroll
      for (int j = 0; j < 8; ++j)
        ef2s[t + j * 256] = ef2g[t + j * 256];
    }
    __syncthreads();

    // --- per wave: S + alpha for rows r=0..3 (n = n0 + 4w + r) ---
    float inv[4];
    bool emptyr[4];
#pragma unroll
    for (int r = 0; r < 4; ++r) {
      const int nl = w * 4 + r, n = n0 + nl;
      float s = 0.f;
#pragma unroll 8
      for (int k = 0; k < N_ / 64; ++k) {
        unsigned long long word = bits[nl][k];
        if ((word >> lane) & 1ull) s += ef2s[k * 64 + lane];
      }
#pragma unroll
      for (int off = 32; off > 0; off >>= 1) s += __shfl_xor(s, off, 64);
      const bool empty = (s == 0.f);
      emptyr[r] = empty;
      const float iv = empty ? 1.0f : (1.f / s);
      inv[r] = iv;
      float* ag = alpha + (bh * N_ + n) * (size_t)N_;
#pragma unroll 4
      for (int k = 0; k < N_ / 64; ++k) {
        unsigned long long word = bits[nl][k];
        float av = ((word >> lane) & 1ull) ? ef2s[k * 64 + lane] * iv : 0.f;
        if (empty) av = invN;
        ag[k * 64 + lane] = av;
      }
    }

    // --- PV: acc[r][e-quad] over m, Wh staged in LDS per m-tile ---
    float4 acc[4];
#pragma unroll
    for (int r = 0; r < 4; ++r) acc[r] = make_float4(0.f, 0.f, 0.f, 0.f);

    const float* Whb = Wh + bh * ((size_t)N_ * DOUT);
    for (int mt = 0; mt < N_; mt += MT) {
      __syncthreads();  // previous tile's readers done
#pragma unroll
      for (int j = 0; j < (MT * DOUT / 4) / 256; ++j) {  // 8 float4 per thread
        int idx = j * 256 + t;
        int mr = idx >> 4, e4 = (idx & 15) * 4;
        *reinterpret_cast<float4*>(&whs[mr][e4]) =
            *reinterpret_cast<const float4*>(Whb + (size_t)(mt + mr) * DOUT + e4);
      }
      __syncthreads();

#pragma unroll
      for (int kb = 0; kb < MT; kb += 64) {
        unsigned long long wq[4];
#pragma unroll
        for (int r = 0; r < 4; ++r)
          wq[r] = bits[w * 4 + r][(mt + kb) >> 6] >> q;  // pre-shift by q
#pragma unroll
        for (int mm = 0; mm < 64; mm += 4) {
          const float ef = ef2s[mt + kb + mm + q];
          const float4 wv = *reinterpret_cast<const float4*>(&whs[kb + mm + q][4 * g]);
#pragma unroll
          for (int r = 0; r < 4; ++r) {
            const unsigned hl =
                (mm < 32) ? (unsigned)wq[r] : (unsigned)(wq[r] >> 32);
            const float tv = ((hl >> (mm & 31)) & 1u) ? ef : 0.f;
            acc[r].x += tv * wv.x; acc[r].y += tv * wv.y;
            acc[r].z += tv * wv.z; acc[r].w += tv * wv.w;
          }
        }
      }
    }

    // --- rare exact path: empty row => uniform alpha = 1/N ---
#pragma unroll
    for (int r = 0; r < 4; ++r) {
      if (emptyr[r]) {  // wave-uniform, effectively never taken
        float4 z = make_float4(0.f, 0.f, 0.f, 0.f);
        for (int m = 0; m < N_; m += 4) {
          const float4 wv =
              *reinterpret_cast<const float4*>(Whb + (size_t)(m + q) * DOUT + 4 * g);
          z.x += invN * wv.x; z.y += invN * wv.y;
          z.z += invN * wv.z; z.w += invN * wv.w;
        }
        acc[r] = z;  // inv[r] == 1
      }
    }

    // --- reduce over q, scale by inv, relu, store ---
#pragma unroll
    for (int r = 0; r < 4; ++r) {
      float4 v = acc[r];
#pragma unroll
      for (int off = 16; off <= 32; off <<= 1) {
        v.x += __shfl_xor(v.x, off, 64);
        v.y += __shfl_xor(v.y, off, 64);
        v.z += __shfl_xor(v.z, off, 64);
        v.w += __shfl_xor(v.w, off, 64);
      }
      const int n = n0 + w * 4 + r;
      if (q == 0) {
        float4 o;
        o.x = fmaxf(v.x * inv[r], 0.f);
        o.y = fmaxf(v.y * inv[r], 0.f);
        o.z = fmaxf(v.z * inv[r], 0.f);
        o.w = fmaxf(v.w * inv[r], 0.f);
        *reinterpret_cast<float4*>(
            out0 + ((size_t)(b * N_ + n)) * (HH * DOUT) + h * DOUT + 4 * g) = o;
      }
    }
  }
}

// ---------------------------------------------------------------------------
extern "C" void kernel_launch(void* const* d_in, const int* in_sizes, int n_in,
                              void* d_out, int out_size, void* d_ws,
                              size_t ws_size, hipStream_t stream) {
  const float* H = (const float*)d_in[0];   // (4,2048,256)
  const int* adj = (const int*)d_in[1];     // (4,2048,2048)
  const float* W = (const float*)d_in[2];   // (8,256,64)
  const float* a = (const float*)d_in[3];   // (8,128)

  float* out = (float*)d_out;
  float* out0 = out;                                 // (4,2048,512)
  float* alpha = out + (size_t)B_ * N_ * HH * DOUT;  // (4,8,2048,2048)

  float* Wh = (float*)d_ws;                       // B*HH*N*DOUT f32
  float* f2 = Wh + (size_t)B_ * HH * N_ * DOUT;
  float* Ef2 = f2 + (size_t)B_ * HH * N_;

  k_wh_f2<<<B_ * HH * (N_ / 16), 256, 0, stream>>>(H, W, a, Wh, f2);
  k_ef2<<<B_ * HH, 256, 0, stream>>>(f2, Ef2);
  k_main<<<B_ * (N_ / 16), 256, 0, stream>>>(adj, Ef2, Wh, out0, alpha);
}

// Round 3
// 708.018 us; speedup vs baseline: 3.3100x; 1.0102x over previous
//
#include <hip/hip_runtime.h>

#define B_  4
#define N_  2048
#define DIN 256
#define DOUT 64
#define HH  8
#define CH  256   // m-chunk per MFMA stage

typedef short s8v __attribute__((ext_vector_type(8)));
typedef float f4v __attribute__((ext_vector_type(4)));

__device__ inline unsigned short bfb(float x) {
  return __builtin_bit_cast(unsigned short, (__bf16)x);
}

// ---------------------------------------------------------------------------
// Kernel 1: Wh = H @ W per head; f2 = Wh . a2; emit Wht (bf16, [bh][e][n])
// block = (bh, 16-row n-tile); 4 waves, each wave 4 rows.
// ---------------------------------------------------------------------------
__global__ __launch_bounds__(256) void k_wh_f2(
    const float* __restrict__ H, const float* __restrict__ W,
    const float* __restrict__ a, unsigned short* __restrict__ Wht,
    float* __restrict__ f2) {
  __shared__ __align__(16) float hs[16][DIN];   // 16 KB
  __shared__ __align__(16) float ows[16][DOUT]; // 4 KB
  const int t = threadIdx.x, w = t >> 6, lane = t & 63;
  const int q = lane >> 4, g = lane & 15;
  const int bh = blockIdx.x >> 7;
  const int tile = blockIdx.x & 127;
  const int b = bh >> 3, h = bh & 7;
  const int n0 = tile * 16;

  const float* Hbase = H + ((size_t)(b * N_ + n0)) * DIN;
#pragma unroll
  for (int j = 0; j < 4; ++j) {
    int idx = j * 256 + t;
    int row = idx >> 6, c4 = idx & 63;
    float4 v = *reinterpret_cast<const float4*>(Hbase + (size_t)row * DIN + c4 * 4);
    *reinterpret_cast<float4*>(&hs[row][c4 * 4]) = v;
  }
  __syncthreads();

  const float* Wp = W + (size_t)h * DIN * DOUT;
  const float4 a2v = *reinterpret_cast<const float4*>(a + h * (2 * DOUT) + DOUT + 4 * g);

  float4 acc[4];
#pragma unroll
  for (int r = 0; r < 4; ++r) acc[r] = make_float4(0.f, 0.f, 0.f, 0.f);

#pragma unroll 4
  for (int d0 = 0; d0 < DIN; d0 += 4) {
    const float4 wv = *reinterpret_cast<const float4*>(Wp + (size_t)(d0 + q) * DOUT + 4 * g);
#pragma unroll
    for (int r = 0; r < 4; ++r) {
      const float hv = hs[w * 4 + r][d0 + q];
      acc[r].x += hv * wv.x; acc[r].y += hv * wv.y;
      acc[r].z += hv * wv.z; acc[r].w += hv * wv.w;
    }
  }

#pragma unroll
  for (int r = 0; r < 4; ++r) {
    float4 v = acc[r];
#pragma unroll
    for (int off = 16; off <= 32; off <<= 1) {
      v.x += __shfl_xor(v.x, off, 64);
      v.y += __shfl_xor(v.y, off, 64);
      v.z += __shfl_xor(v.z, off, 64);
      v.w += __shfl_xor(v.w, off, 64);
    }
    const int n = n0 + w * 4 + r;
    if (q == 0) *reinterpret_cast<float4*>(&ows[w * 4 + r][4 * g]) = v;
    float fr = v.x * a2v.x + v.y * a2v.y + v.z * a2v.z + v.w * a2v.w;
    fr += __shfl_xor(fr, 1, 64);
    fr += __shfl_xor(fr, 2, 64);
    fr += __shfl_xor(fr, 4, 64);
    fr += __shfl_xor(fr, 8, 64);
    if (lane == 0) f2[(size_t)bh * N_ + n] = fr;
  }
  __syncthreads();

  // transpose out: Wht[bh][e][n0+i4..+4] as bf16
  const int e = t & 63, i4 = (t >> 6) * 4;
  ushort4 pkv;
  pkv.x = bfb(ows[i4 + 0][e]);
  pkv.y = bfb(ows[i4 + 1][e]);
  pkv.z = bfb(ows[i4 + 2][e]);
  pkv.w = bfb(ows[i4 + 3][e]);
  *reinterpret_cast<ushort4*>(Wht + ((size_t)bh * DOUT + e) * N_ + n0 + i4) = pkv;
}

// ---------------------------------------------------------------------------
// Kernel 1b: per (b,h): mx = max_m f2; Ef2[m] = exp(f2[m]-mx)
// ---------------------------------------------------------------------------
__global__ __launch_bounds__(256) void k_ef2(const float* __restrict__ f2,
                                             float* __restrict__ Ef2) {
  __shared__ float red[256];
  const int bh = blockIdx.x;
  const int t = threadIdx.x;
  const float* src = f2 + (size_t)bh * N_;
  float v[8];
  float mx = -1e30f;
#pragma unroll
  for (int j = 0; j < 8; ++j) {
    v[j] = src[t + j * 256];
    mx = fmaxf(mx, v[j]);
  }
  red[t] = mx;
  __syncthreads();
  for (int s = 128; s > 0; s >>= 1) {
    if (t < s) red[t] = fmaxf(red[t], red[t + s]);
    __syncthreads();
  }
  mx = red[0];
  float* dst = Ef2 + (size_t)bh * N_;
#pragma unroll
  for (int j = 0; j < 8; ++j) dst[t + j * 256] = __expf(v[j] - mx);
}

// ---------------------------------------------------------------------------
// Kernel 2: per block = (b, 16-row n-tile). MFMA PV.
// wave w owns e-block [16w,16w+16); rows = the 16-row tile (MFMA M dim).
// ---------------------------------------------------------------------------
__global__ __launch_bounds__(256) void k_main(
    const int* __restrict__ adj, const float* __restrict__ Ef2,
    const unsigned short* __restrict__ WhtG, float* __restrict__ out0,
    float* __restrict__ alpha) {
  __shared__ float ef2s[N_];                              // 8 KB
  __shared__ unsigned long long bits[16][N_ / 64];        // 4 KB
  __shared__ __align__(16) unsigned short asp[16 * CH];   // 8 KB  (swizzled)
  __shared__ __align__(16) unsigned short whs[64 * CH];   // 32 KB (swizzled)

  const int t = threadIdx.x, w = t >> 6, lane = t & 63;
  const int b = blockIdx.x >> 7;
  const int n0 = (blockIdx.x & 127) * 16;
  const float invN = 1.f / (float)N_;
  const int gr = lane >> 4;   // 0..3
  const int gc = lane & 15;   // 0..15
  const int r = 4 * w + gr;   // this thread's alpha row (0..15)

  // --- pack adjacency bits ---
  for (int nl = 0; nl < 16; ++nl) {
    const int* arow = adj + ((size_t)(b * N_ + n0 + nl)) * N_;
#pragma unroll
    for (int i = 0; i < 8; ++i) {
      unsigned long long msk = __ballot(arow[w * 512 + i * 64 + lane] != 0);
      if (lane == 0) bits[nl][w * 8 + i] = msk;
    }
  }
  __syncthreads();

  for (int h = 0; h < HH; ++h) {
    const size_t bh = (size_t)(b * HH + h);
    __syncthreads();
    {
      const float* ef2g = Ef2 + bh * N_;
#pragma unroll
      for (int j = 0; j < 8; ++j) ef2s[t + j * 256] = ef2g[t + j * 256];
    }
    __syncthreads();

    // --- S-pass: wave w computes S for rows 4w..4w+3 ---
    float sArr[4];
#pragma unroll
    for (int rr = 0; rr < 4; ++rr) {
      const int nl = w * 4 + rr;
      float s = 0.f;
#pragma unroll 8
      for (int k = 0; k < N_ / 64; ++k) {
        unsigned long long word = bits[nl][k];
        if ((word >> lane) & 1ull) s += ef2s[k * 64 + lane];
      }
#pragma unroll
      for (int off = 32; off > 0; off >>= 1) s += __shfl_xor(s, off, 64);
      sArr[rr] = s;
    }
    const float sMy = gr == 0 ? sArr[0] : gr == 1 ? sArr[1] : gr == 2 ? sArr[2] : sArr[3];
    const bool emp = (sMy == 0.f);
    const float iv = emp ? 0.f : 1.f / sMy;

    f4v acc = {0.f, 0.f, 0.f, 0.f};
    const unsigned short* WhtB = WhtG + bh * ((size_t)DOUT * N_);
    float* alphaRow = alpha + (bh * N_ + (size_t)(n0 + r)) * N_;

    for (int mc = 0; mc < N_; mc += CH) {
      // issue Wht chunk loads early (no LDS dependency -> before barrier)
      uint4 vv[8];
      int eI[8], sI[8];
#pragma unroll
      for (int i = 0; i < 8; ++i) {
        int idx = i * 256 + t;
        int e = idx >> 5;       // 0..63
        int s16 = idx & 31;     // 16B segment within 512B row
        eI[i] = e; sI[i] = s16;
        vv[i] = *reinterpret_cast<const uint4*>(
            (const char*)(WhtB + (size_t)e * N_ + mc) + s16 * 16);
      }
      __syncthreads();  // prior chunk's MFMA reads done

      // --- generate alpha (f32 -> global) + asp (bf16 A-fragments) ---
      {
        unsigned long long wd = bits[r][(mc >> 6) + (gc >> 2)];
        unsigned msk = (unsigned)(wd >> ((gc & 3) * 16)) & 0xFFFFu;
        const float4* ef4 = reinterpret_cast<const float4*>(&ef2s[mc + gc * 16]);
        union { unsigned short u16[16]; uint4 q4[2]; } pk;
#pragma unroll
        for (int j4 = 0; j4 < 4; ++j4) {
          const float4 ev = ef4[j4];
          float a0 = ((msk >> (j4 * 4 + 0)) & 1u) ? ev.x * iv : 0.f;
          float a1 = ((msk >> (j4 * 4 + 1)) & 1u) ? ev.y * iv : 0.f;
          float a2 = ((msk >> (j4 * 4 + 2)) & 1u) ? ev.z * iv : 0.f;
          float a3 = ((msk >> (j4 * 4 + 3)) & 1u) ? ev.w * iv : 0.f;
          a0 = emp ? invN : a0;
          a1 = emp ? invN : a1;
          a2 = emp ? invN : a2;
          a3 = emp ? invN : a3;
          *reinterpret_cast<float4*>(alphaRow + mc + gc * 16 + j4 * 4) =
              make_float4(a0, a1, a2, a3);
          pk.u16[j4 * 4 + 0] = bfb(a0);
          pk.u16[j4 * 4 + 1] = bfb(a1);
          pk.u16[j4 * 4 + 2] = bfb(a2);
          pk.u16[j4 * 4 + 3] = bfb(a3);
        }
        const int k7 = r & 7;
        *reinterpret_cast<uint4*>((char*)asp + r * (CH * 2) + ((gc * 2) ^ k7) * 16) = pk.q4[0];
        *reinterpret_cast<uint4*>((char*)asp + r * (CH * 2) + ((gc * 2 + 1) ^ k7) * 16) = pk.q4[1];
      }

      // --- write staged Wht chunk to LDS (swizzled) ---
#pragma unroll
      for (int i = 0; i < 8; ++i) {
        int byteoff = eI[i] * (CH * 2) + ((sI[i] ^ (eI[i] & 7)) * 16);
        *reinterpret_cast<uint4*>((char*)whs + byteoff) = vv[i];
      }
      __syncthreads();

      // --- MFMA: 8 K=32 fragments ---
#pragma unroll
      for (int f = 0; f < 8; ++f) {
        const int seg = f * 4 + gr;
        const int k7 = gc & 7;
        s8v af = *reinterpret_cast<const s8v*>(
            (const char*)asp + gc * (CH * 2) + ((seg ^ k7) * 16));
        const int eR = 16 * w + gc;
        s8v bfr = *reinterpret_cast<const s8v*>(
            (const char*)whs + eR * (CH * 2) + ((seg ^ k7) * 16));
        acc = __builtin_amdgcn_mfma_f32_16x16x32_bf16(af, bfr, acc, 0, 0, 0);
      }
    }

    // --- epilogue: C/D layout col=lane&15, row=(lane>>4)*4+reg ---
    {
      float* op = out0 + ((size_t)(b * N_ + n0 + gr * 4)) * (HH * DOUT) +
                  h * DOUT + 16 * w + gc;
#pragma unroll
      for (int j = 0; j < 4; ++j) {
        op[(size_t)j * (HH * DOUT)] = fmaxf(acc[j], 0.f);
      }
    }
  }
}

// ---------------------------------------------------------------------------
extern "C" void kernel_launch(void* const* d_in, const int* in_sizes, int n_in,
                              void* d_out, int out_size, void* d_ws,
                              size_t ws_size, hipStream_t stream) {
  const float* H = (const float*)d_in[0];   // (4,2048,256)
  const int* adj = (const int*)d_in[1];     // (4,2048,2048)
  const float* W = (const float*)d_in[2];   // (8,256,64)
  const float* a = (const float*)d_in[3];   // (8,128)

  float* out = (float*)d_out;
  float* out0 = out;                                 // (4,2048,512)
  float* alpha = out + (size_t)B_ * N_ * HH * DOUT;  // (4,8,2048,2048)

  unsigned short* Wht = (unsigned short*)d_ws;            // bf16 [bh][e][n]
  float* f2 = (float*)(Wht + (size_t)B_ * HH * DOUT * N_);
  float* Ef2 = f2 + (size_t)B_ * HH * N_;

  k_wh_f2<<<B_ * HH * (N_ / 16), 256, 0, stream>>>(H, W, a, Wht, f2);
  k_ef2<<<B_ * HH, 256, 0, stream>>>(f2, Ef2);
  k_main<<<B_ * (N_ / 16), 256, 0, stream>>>(adj, Ef2, Wht, out0, alpha);
}

// Round 4
// 440.859 us; speedup vs baseline: 5.3159x; 1.6060x over previous
//
#include <hip/hip_runtime.h>

#define B_  4
#define N_  2048
#define DIN 256
#define DOUT 64
#define HH  8
#define CH  256   // m-chunk per MFMA stage

typedef short s8v __attribute__((ext_vector_type(8)));
typedef float f4v __attribute__((ext_vector_type(4)));

__device__ inline unsigned short bfb(float x) {
  return __builtin_bit_cast(unsigned short, (__bf16)x);
}

// ---------------------------------------------------------------------------
// Kernel 1: Wh = H @ W per head; f2 = Wh . a2
// Wht layout: [bh][tile=n/16][e][16]  (bf16) -> block writes 2KB contiguous.
// ---------------------------------------------------------------------------
__global__ __launch_bounds__(256) void k_wh_f2(
    const float* __restrict__ H, const float* __restrict__ W,
    const float* __restrict__ a, unsigned short* __restrict__ Wht,
    float* __restrict__ f2) {
  __shared__ __align__(16) float hs[16][DIN];    // 16 KB
  __shared__ __align__(16) float ows[DOUT][20];  // 5 KB, transposed + padded
  const int t = threadIdx.x, w = t >> 6, lane = t & 63;
  const int q = lane >> 4, g = lane & 15;
  const int bh = blockIdx.x >> 7;
  const int tile = blockIdx.x & 127;
  const int b = bh >> 3, h = bh & 7;
  const int n0 = tile * 16;

  const float* Hbase = H + ((size_t)(b * N_ + n0)) * DIN;
#pragma unroll
  for (int j = 0; j < 4; ++j) {
    int idx = j * 256 + t;
    int row = idx >> 6, c4 = idx & 63;
    float4 v = *reinterpret_cast<const float4*>(Hbase + (size_t)row * DIN + c4 * 4);
    *reinterpret_cast<float4*>(&hs[row][c4 * 4]) = v;
  }
  __syncthreads();

  const float* Wp = W + (size_t)h * DIN * DOUT;
  const float4 a2v = *reinterpret_cast<const float4*>(a + h * (2 * DOUT) + DOUT + 4 * g);

  float4 acc[4];
#pragma unroll
  for (int r = 0; r < 4; ++r) acc[r] = make_float4(0.f, 0.f, 0.f, 0.f);

#pragma unroll 4
  for (int d0 = 0; d0 < DIN; d0 += 4) {
    const float4 wv = *reinterpret_cast<const float4*>(Wp + (size_t)(d0 + q) * DOUT + 4 * g);
#pragma unroll
    for (int r = 0; r < 4; ++r) {
      const float hv = hs[w * 4 + r][d0 + q];
      acc[r].x += hv * wv.x; acc[r].y += hv * wv.y;
      acc[r].z += hv * wv.z; acc[r].w += hv * wv.w;
    }
  }

#pragma unroll
  for (int r = 0; r < 4; ++r) {
    float4 v = acc[r];
#pragma unroll
    for (int off = 16; off <= 32; off <<= 1) {
      v.x += __shfl_xor(v.x, off, 64);
      v.y += __shfl_xor(v.y, off, 64);
      v.z += __shfl_xor(v.z, off, 64);
      v.w += __shfl_xor(v.w, off, 64);
    }
    const int n = n0 + w * 4 + r;
    if (q == 0) {
      ows[4 * g + 0][w * 4 + r] = v.x;
      ows[4 * g + 1][w * 4 + r] = v.y;
      ows[4 * g + 2][w * 4 + r] = v.z;
      ows[4 * g + 3][w * 4 + r] = v.w;
    }
    float fr = v.x * a2v.x + v.y * a2v.y + v.z * a2v.z + v.w * a2v.w;
    fr += __shfl_xor(fr, 1, 64);
    fr += __shfl_xor(fr, 2, 64);
    fr += __shfl_xor(fr, 4, 64);
    fr += __shfl_xor(fr, 8, 64);
    if (lane == 0) f2[(size_t)bh * N_ + n] = fr;
  }
  __syncthreads();

  // write tile: thread t -> elements [t*4, t*4+4) of the 64x16 tile
  {
    const int e = t >> 2, ibase = (t & 3) * 4;
    float4 f = *reinterpret_cast<const float4*>(&ows[e][ibase]);
    ushort4 pkv;
    pkv.x = bfb(f.x); pkv.y = bfb(f.y); pkv.z = bfb(f.z); pkv.w = bfb(f.w);
    *reinterpret_cast<ushort4*>(Wht + ((size_t)bh * 128 + tile) * 1024 + t * 4) = pkv;
  }
}

// ---------------------------------------------------------------------------
// Kernel 1b: per (b,h): mx = max_m f2; Ef2[m] = exp(f2[m]-mx)
// ---------------------------------------------------------------------------
__global__ __launch_bounds__(256) void k_ef2(const float* __restrict__ f2,
                                             float* __restrict__ Ef2) {
  __shared__ float red[256];
  const int bh = blockIdx.x;
  const int t = threadIdx.x;
  const float* src = f2 + (size_t)bh * N_;
  float v[8];
  float mx = -1e30f;
#pragma unroll
  for (int j = 0; j < 8; ++j) {
    v[j] = src[t + j * 256];
    mx = fmaxf(mx, v[j]);
  }
  red[t] = mx;
  __syncthreads();
  for (int s = 128; s > 0; s >>= 1) {
    if (t < s) red[t] = fmaxf(red[t], red[t + s]);
    __syncthreads();
  }
  mx = red[0];
  float* dst = Ef2 + (size_t)bh * N_;
#pragma unroll
  for (int j = 0; j < 8; ++j) dst[t + j * 256] = __expf(v[j] - mx);
}

// ---------------------------------------------------------------------------
// Kernel 2: per block = (b, 16-row n-tile). MFMA PV, coalesced alpha stores.
// ---------------------------------------------------------------------------
__global__ __launch_bounds__(256) void k_main(
    const int* __restrict__ adj, const float* __restrict__ Ef2,
    const unsigned short* __restrict__ WhtG, float* __restrict__ out0,
    float* __restrict__ alpha) {
  __shared__ float ef2s[N_];                              // 8 KB
  __shared__ unsigned long long bits[16][N_ / 64];        // 4 KB
  __shared__ __align__(16) unsigned short asp[16 * CH];   // 8 KB  (swizzled)
  __shared__ __align__(16) unsigned short whs[64 * CH];   // 32 KB (swizzled)

  const int t = threadIdx.x, w = t >> 6, lane = t & 63;
  // bijective XCD swizzle: 512 blocks = 8 XCDs x 64
  const int wg = (blockIdx.x & 7) * 64 + (blockIdx.x >> 3);
  const int b = wg >> 7;
  const int n0 = (wg & 127) * 16;
  const float invN = 1.f / (float)N_;
  const int gr = lane >> 4;   // 0..3
  const int gc = lane & 15;   // 0..15
  const int r = 4 * w + gr;   // this thread's alpha row (0..15)
  const int k7 = r & 7;

  // --- pack adjacency bits ---
  for (int nl = 0; nl < 16; ++nl) {
    const int* arow = adj + ((size_t)(b * N_ + n0 + nl)) * N_;
#pragma unroll
    for (int i = 0; i < 8; ++i) {
      unsigned long long msk = __ballot(arow[w * 512 + i * 64 + lane] != 0);
      if (lane == 0) bits[nl][w * 8 + i] = msk;
    }
  }
  __syncthreads();

  for (int h = 0; h < HH; ++h) {
    const size_t bh = (size_t)(b * HH + h);
    __syncthreads();
    {
      const float* ef2g = Ef2 + bh * N_;
#pragma unroll
      for (int j = 0; j < 8; ++j) ef2s[t + j * 256] = ef2g[t + j * 256];
    }
    __syncthreads();

    // --- S-pass: wave w computes S for rows 4w..4w+3 ---
    float sArr[4];
#pragma unroll
    for (int rr = 0; rr < 4; ++rr) {
      const int nl = w * 4 + rr;
      float s = 0.f;
#pragma unroll 8
      for (int k = 0; k < N_ / 64; ++k) {
        unsigned long long word = bits[nl][k];
        if ((word >> lane) & 1ull) s += ef2s[k * 64 + lane];
      }
#pragma unroll
      for (int off = 32; off > 0; off >>= 1) s += __shfl_xor(s, off, 64);
      sArr[rr] = s;
    }
    const float sMy = gr == 0 ? sArr[0] : gr == 1 ? sArr[1] : gr == 2 ? sArr[2] : sArr[3];
    const bool emp = (sMy == 0.f);
    const float iv = emp ? 0.f : 1.f / sMy;

    f4v acc = {0.f, 0.f, 0.f, 0.f};
    // Wht chunk region for this bh: [bh][tile][e][16], chunk = 16 tiles = 32KB
    const unsigned short* WhtB = WhtG + (size_t)bh * (128 * 1024);
    float* alphaRow = alpha + (bh * N_ + (size_t)(n0 + r)) * N_;

    for (int mc = 0; mc < N_; mc += CH) {
      // issue contiguous 32KB chunk loads early (no LDS dependency)
      uint4 vv[8];
      const uint4* src = reinterpret_cast<const uint4*>(WhtB + (size_t)(mc >> 4) * 1024);
#pragma unroll
      for (int i = 0; i < 8; ++i) vv[i] = src[i * 256 + t];

      __syncthreads();  // prior chunk's MFMA reads done

      // --- alpha: f32 coalesced NT store + bf16 A-fragments ---
#pragma unroll
      for (int j4 = 0; j4 < 4; ++j4) {
        const unsigned long long word = bits[r][(mc >> 6) + j4];
        const unsigned nib = (unsigned)(word >> (gc * 4)) & 0xFu;
        const float4 ev = *reinterpret_cast<const float4*>(&ef2s[mc + j4 * 64 + gc * 4]);
        float a0 = (nib & 1u) ? ev.x * iv : 0.f;
        float a1 = (nib & 2u) ? ev.y * iv : 0.f;
        float a2 = (nib & 4u) ? ev.z * iv : 0.f;
        float a3 = (nib & 8u) ? ev.w * iv : 0.f;
        a0 = emp ? invN : a0;
        a1 = emp ? invN : a1;
        a2 = emp ? invN : a2;
        a3 = emp ? invN : a3;
        f4v av4 = {a0, a1, a2, a3};
        __builtin_nontemporal_store(
            av4, reinterpret_cast<f4v*>(alphaRow + mc + j4 * 64 + gc * 4));
        union { unsigned short u16[4]; uint2 v2; } pk;
        pk.u16[0] = bfb(a0); pk.u16[1] = bfb(a1);
        pk.u16[2] = bfb(a2); pk.u16[3] = bfb(a3);
        // 8B granule g8 = j4*16+gc of row r, XOR-swizzled at 16B level
        const int byteoff =
            r * (CH * 2) + (((j4 * 8 + (gc >> 1)) ^ k7) * 16) + ((gc & 1) * 8);
        *reinterpret_cast<uint2*>((char*)asp + byteoff) = pk.v2;
      }

      // --- write staged Wht chunk to LDS (swizzled) ---
#pragma unroll
      for (int i = 0; i < 8; ++i) {
        const int o = i * 256 + t;              // 16B granule of [tile][e][16]
        const int e = (o & 127) >> 1;
        const int gseg = ((o >> 7) << 1) | (o & 1);  // n-granule 0..31
        *reinterpret_cast<uint4*>((char*)whs + e * (CH * 2) +
                                  ((gseg ^ (e & 7)) * 16)) = vv[i];
      }
      __syncthreads();

      // --- MFMA: 8 K=32 fragments ---
#pragma unroll
      for (int f = 0; f < 8; ++f) {
        const int seg = f * 4 + gr;
        const int k7g = gc & 7;
        s8v af = *reinterpret_cast<const s8v*>(
            (const char*)asp + gc * (CH * 2) + ((seg ^ k7g) * 16));
        const int eR = 16 * w + gc;
        s8v bfr = *reinterpret_cast<const s8v*>(
            (const char*)whs + eR * (CH * 2) + ((seg ^ k7g) * 16));
        acc = __builtin_amdgcn_mfma_f32_16x16x32_bf16(af, bfr, acc, 0, 0, 0);
      }
    }

    // --- epilogue: C/D layout col=lane&15, row=(lane>>4)*4+reg ---
    {
      float* op = out0 + ((size_t)(b * N_ + n0 + gr * 4)) * (HH * DOUT) +
                  h * DOUT + 16 * w + gc;
#pragma unroll
      for (int j = 0; j < 4; ++j) {
        op[(size_t)j * (HH * DOUT)] = fmaxf(acc[j], 0.f);
      }
    }
  }
}

// ---------------------------------------------------------------------------
extern "C" void kernel_launch(void* const* d_in, const int* in_sizes, int n_in,
                              void* d_out, int out_size, void* d_ws,
                              size_t ws_size, hipStream_t stream) {
  const float* H = (const float*)d_in[0];   // (4,2048,256)
  const int* adj = (const int*)d_in[1];     // (4,2048,2048)
  const float* W = (const float*)d_in[2];   // (8,256,64)
  const float* a = (const float*)d_in[3];   // (8,128)

  float* out = (float*)d_out;
  float* out0 = out;                                 // (4,2048,512)
  float* alpha = out + (size_t)B_ * N_ * HH * DOUT;  // (4,8,2048,2048)

  unsigned short* Wht = (unsigned short*)d_ws;  // bf16 [bh][tile][e][16]
  float* f2 = (float*)(Wht + (size_t)B_ * HH * DOUT * N_);
  float* Ef2 = f2 + (size_t)B_ * HH * N_;

  k_wh_f2<<<B_ * HH * (N_ / 16), 256, 0, stream>>>(H, W, a, Wht, f2);
  k_ef2<<<B_ * HH, 256, 0, stream>>>(f2, Ef2);
  k_main<<<B_ * (N_ / 16), 256, 0, stream>>>(adj, Ef2, Wht, out0, alpha);
}

// Round 5
// 205.478 us; speedup vs baseline: 11.4053x; 2.1455x over previous
//
#include <hip/hip_runtime.h>

#define B_  4
#define N_  2048
#define DIN 256
#define DOUT 64
#define HH  8
#define CH  256   // m-chunk (register blocking only; no LDS staging)

typedef short s8v __attribute__((ext_vector_type(8)));
typedef float f4v __attribute__((ext_vector_type(4)));

__device__ inline unsigned short bfb(float x) {
  return __builtin_bit_cast(unsigned short, (__bf16)x);
}

// ---------------------------------------------------------------------------
// Kernel 1: Wh = H @ W per head; f2 = Wh . a2
// Wht layout: [bh][seg=n/32][e][32] bf16  (B-fragment-friendly, coalesced)
// block = (bh, 16-row tile); 4 waves.
// ---------------------------------------------------------------------------
__global__ __launch_bounds__(256) void k_wh_f2(
    const float* __restrict__ H, const float* __restrict__ W,
    const float* __restrict__ a, unsigned short* __restrict__ Wht,
    float* __restrict__ f2) {
  __shared__ __align__(16) float hs[16][DIN];    // 16 KB
  __shared__ __align__(16) float ows[DOUT][20];  // 5 KB (ows[e][n_local], padded)
  const int t = threadIdx.x, w = t >> 6, lane = t & 63;
  const int q = lane >> 4, g = lane & 15;
  const int bh = blockIdx.x >> 7;
  const int tile = blockIdx.x & 127;
  const int b = bh >> 3, h = bh & 7;
  const int n0 = tile * 16;

  const float* Hbase = H + ((size_t)(b * N_ + n0)) * DIN;
#pragma unroll
  for (int j = 0; j < 4; ++j) {
    int idx = j * 256 + t;
    int row = idx >> 6, c4 = idx & 63;
    float4 v = *reinterpret_cast<const float4*>(Hbase + (size_t)row * DIN + c4 * 4);
    *reinterpret_cast<float4*>(&hs[row][c4 * 4]) = v;
  }
  __syncthreads();

  const float* Wp = W + (size_t)h * DIN * DOUT;
  const float4 a2v = *reinterpret_cast<const float4*>(a + h * (2 * DOUT) + DOUT + 4 * g);

  float4 acc[4];
#pragma unroll
  for (int r = 0; r < 4; ++r) acc[r] = make_float4(0.f, 0.f, 0.f, 0.f);

#pragma unroll 4
  for (int d0 = 0; d0 < DIN; d0 += 4) {
    const float4 wv = *reinterpret_cast<const float4*>(Wp + (size_t)(d0 + q) * DOUT + 4 * g);
#pragma unroll
    for (int r = 0; r < 4; ++r) {
      const float hv = hs[w * 4 + r][d0 + q];
      acc[r].x += hv * wv.x; acc[r].y += hv * wv.y;
      acc[r].z += hv * wv.z; acc[r].w += hv * wv.w;
    }
  }

#pragma unroll
  for (int r = 0; r < 4; ++r) {
    float4 v = acc[r];
#pragma unroll
    for (int off = 16; off <= 32; off <<= 1) {
      v.x += __shfl_xor(v.x, off, 64);
      v.y += __shfl_xor(v.y, off, 64);
      v.z += __shfl_xor(v.z, off, 64);
      v.w += __shfl_xor(v.w, off, 64);
    }
    const int n = n0 + w * 4 + r;
    if (q == 0) {
      ows[4 * g + 0][w * 4 + r] = v.x;
      ows[4 * g + 1][w * 4 + r] = v.y;
      ows[4 * g + 2][w * 4 + r] = v.z;
      ows[4 * g + 3][w * 4 + r] = v.w;
    }
    float fr = v.x * a2v.x + v.y * a2v.y + v.z * a2v.z + v.w * a2v.w;
    fr += __shfl_xor(fr, 1, 64);
    fr += __shfl_xor(fr, 2, 64);
    fr += __shfl_xor(fr, 4, 64);
    fr += __shfl_xor(fr, 8, 64);
    if (lane == 0) f2[(size_t)bh * N_ + n] = fr;
  }
  __syncthreads();

  // write tile into [bh][seg][e][32]: seg = tile>>1, half = tile&1
  {
    const int e = t >> 2, quad = t & 3;
    const int seg = tile >> 1, half = tile & 1;
    float4 f = *reinterpret_cast<const float4*>(&ows[e][quad * 4]);
    ushort4 pkv;
    pkv.x = bfb(f.x); pkv.y = bfb(f.y); pkv.z = bfb(f.z); pkv.w = bfb(f.w);
    *reinterpret_cast<ushort4*>(Wht + (size_t)bh * (DOUT * N_) +
                                ((size_t)seg * 64 + e) * 32 + half * 16 + quad * 4) = pkv;
  }
}

// ---------------------------------------------------------------------------
// Kernel 1b: per (b,h): mx = max_m f2; Ef2[m] = exp(f2[m]-mx)
// ---------------------------------------------------------------------------
__global__ __launch_bounds__(256) void k_ef2(const float* __restrict__ f2,
                                             float* __restrict__ Ef2) {
  __shared__ float red[256];
  const int bh = blockIdx.x;
  const int t = threadIdx.x;
  const float* src = f2 + (size_t)bh * N_;
  float v[8];
  float mx = -1e30f;
#pragma unroll
  for (int j = 0; j < 8; ++j) {
    v[j] = src[t + j * 256];
    mx = fmaxf(mx, v[j]);
  }
  red[t] = mx;
  __syncthreads();
  for (int s = 128; s > 0; s >>= 1) {
    if (t < s) red[t] = fmaxf(red[t], red[t + s]);
    __syncthreads();
  }
  mx = red[0];
  float* dst = Ef2 + (size_t)bh * N_;
#pragma unroll
  for (int j = 0; j < 8; ++j) dst[t + j * 256] = __expf(v[j] - mx);
}

// ---------------------------------------------------------------------------
// Kernel 1c: pack adjacency bits: bitsG[b][tile][16 rows][32 words of 64]
// 512 blocks (b,tile).
// ---------------------------------------------------------------------------
__global__ __launch_bounds__(256) void k_pack(const int* __restrict__ adj,
                                              unsigned long long* __restrict__ bitsG) {
  __shared__ unsigned long long lb[16][32];
  const int t = threadIdx.x, w = t >> 6, lane = t & 63;
  const int b = blockIdx.x >> 7;
  const int n0 = (blockIdx.x & 127) * 16;
  for (int nl = 0; nl < 16; ++nl) {
    const int* arow = adj + ((size_t)(b * N_ + n0 + nl)) * N_;
#pragma unroll
    for (int i = 0; i < 8; ++i) {
      unsigned long long msk = __ballot(arow[w * 512 + i * 64 + lane] != 0);
      if (lane == 0) lb[nl][w * 8 + i] = msk;
    }
  }
  __syncthreads();
  reinterpret_cast<uint4*>(bitsG + (size_t)blockIdx.x * 512)[t] =
      reinterpret_cast<const uint4*>(lb)[t];
}

// ---------------------------------------------------------------------------
// Kernel 2: block = (bh, 16-row tile) -> 4096 blocks, ONE head each.
// No barriers in the K loop: A-fragments in registers, B-fragments direct
// global->VGPR, alpha NT-stored.
// ---------------------------------------------------------------------------
__global__ __launch_bounds__(256, 4) void k_main(
    const unsigned long long* __restrict__ bitsG, const float* __restrict__ Ef2,
    const unsigned short* __restrict__ WhtG, float* __restrict__ out0,
    float* __restrict__ alpha) {
  __shared__ __align__(16) float ef2s[N_];                 // 8 KB
  __shared__ __align__(16) unsigned long long bits[16][32];  // 4 KB
  __shared__ float ivs[16];
  __shared__ float eas[16];

  const int t = threadIdx.x, w = t >> 6, lane = t & 63;
  const int gr = lane >> 4;   // 0..3
  const int gc = lane & 15;   // 0..15
  // bijective XCD swizzle: 4096 = 8 XCDs x 512; same-XCD blocks share (b,h)
  const int wg = (blockIdx.x & 7) * 512 + (blockIdx.x >> 3);
  const int bh = wg >> 7;                  // 0..31
  const int tile = wg & 127;
  const int b = bh >> 3, h = bh & 7;
  const int n0 = tile * 16;
  const int r = 4 * w + gr;                // alpha-write row (0..15)
  const float invN = 1.f / (float)N_;

  // --- stage bits (4 KB) and ef2s (8 KB) ---
  reinterpret_cast<uint4*>(&bits[0][0])[t] =
      reinterpret_cast<const uint4*>(bitsG + ((size_t)(b * 128 + tile)) * 512)[t];
  {
    const float4* src = reinterpret_cast<const float4*>(Ef2 + (size_t)bh * N_);
    float4* dst = reinterpret_cast<float4*>(ef2s);
    dst[t] = src[t];
    dst[t + 256] = src[t + 256];
  }
  __syncthreads();

  // --- S-pass: wave w handles rows 4w..4w+3, joint k-loop (shared ef read) ---
  {
    float s0 = 0.f, s1 = 0.f, s2 = 0.f, s3 = 0.f;
#pragma unroll 4
    for (int k = 0; k < 32; ++k) {
      const float ef = ef2s[k * 64 + lane];
      const unsigned long long w0 = bits[4 * w + 0][k];
      const unsigned long long w1 = bits[4 * w + 1][k];
      const unsigned long long w2 = bits[4 * w + 2][k];
      const unsigned long long w3 = bits[4 * w + 3][k];
      s0 += ((w0 >> lane) & 1ull) ? ef : 0.f;
      s1 += ((w1 >> lane) & 1ull) ? ef : 0.f;
      s2 += ((w2 >> lane) & 1ull) ? ef : 0.f;
      s3 += ((w3 >> lane) & 1ull) ? ef : 0.f;
    }
#pragma unroll
    for (int off = 32; off > 0; off >>= 1) {
      s0 += __shfl_xor(s0, off, 64);
      s1 += __shfl_xor(s1, off, 64);
      s2 += __shfl_xor(s2, off, 64);
      s3 += __shfl_xor(s3, off, 64);
    }
    if (lane == 0) {
      float sv[4] = {s0, s1, s2, s3};
#pragma unroll
      for (int rr = 0; rr < 4; ++rr) {
        const bool emp = (sv[rr] == 0.f);
        ivs[4 * w + rr] = emp ? 0.f : 1.f / sv[rr];
        eas[4 * w + rr] = emp ? invN : 0.f;
      }
    }
  }
  __syncthreads();

  const float ivR = ivs[r], eaR = eas[r];     // write-partition row
  const float ivA = ivs[gc], eaA = eas[gc];   // MFMA A-partition row
  const unsigned* bitsU = reinterpret_cast<const unsigned*>(&bits[0][0]);  // [16][64]

  const char* WhtB = reinterpret_cast<const char*>(WhtG + (size_t)bh * (DOUT * N_));
  float* alphaRow = alpha + ((size_t)bh * N_ + (size_t)(n0 + r)) * N_;
  f4v acc = {0.f, 0.f, 0.f, 0.f};

  for (int mc = 0; mc < N_; mc += CH) {
    // --- B-fragment loads (coalesced 1KB/wave/frag), issued first ---
    uint4 bfrag[8];
#pragma unroll
    for (int f = 0; f < 8; ++f) {
      bfrag[f] = *reinterpret_cast<const uint4*>(
          WhtB + (((size_t)((mc >> 5) + f) * 64 + 16 * w + gc) * 32 + gr * 8) * 2);
    }

    // --- alpha: coalesced NT f32 stores (row r, cols gc*4 + 64*j4) ---
#pragma unroll
    for (int j4 = 0; j4 < 4; ++j4) {
      const unsigned long long word = bits[r][(mc >> 6) + j4];
      const unsigned nib = (unsigned)(word >> (gc * 4)) & 0xFu;
      const float4 ev = *reinterpret_cast<const float4*>(&ef2s[mc + j4 * 64 + gc * 4]);
      f4v av4;
      av4[0] = ((nib & 1u) ? ev.x * ivR : 0.f) + eaR;
      av4[1] = ((nib & 2u) ? ev.y * ivR : 0.f) + eaR;
      av4[2] = ((nib & 4u) ? ev.z * ivR : 0.f) + eaR;
      av4[3] = ((nib & 8u) ? ev.w * ivR : 0.f) + eaR;
      __builtin_nontemporal_store(
          av4, reinterpret_cast<f4v*>(alphaRow + mc + j4 * 64 + gc * 4));
    }

    // --- MFMA: A-fragments generated in registers (row gc, k=f*32+gr*8+j) ---
#pragma unroll
    for (int f = 0; f < 8; ++f) {
      const unsigned u32w = bitsU[gc * 64 + (mc >> 5) + f];
      const unsigned byte = (u32w >> (gr * 8)) & 0xFFu;
      const float4 e0 = *reinterpret_cast<const float4*>(&ef2s[mc + f * 32 + gr * 8]);
      const float4 e1 = *reinterpret_cast<const float4*>(&ef2s[mc + f * 32 + gr * 8 + 4]);
      union { unsigned short u[8]; s8v v; } ap;
      ap.u[0] = bfb(((byte & 1u) ? e0.x * ivA : 0.f) + eaA);
      ap.u[1] = bfb(((byte & 2u) ? e0.y * ivA : 0.f) + eaA);
      ap.u[2] = bfb(((byte & 4u) ? e0.z * ivA : 0.f) + eaA);
      ap.u[3] = bfb(((byte & 8u) ? e0.w * ivA : 0.f) + eaA);
      ap.u[4] = bfb(((byte & 16u) ? e1.x * ivA : 0.f) + eaA);
      ap.u[5] = bfb(((byte & 32u) ? e1.y * ivA : 0.f) + eaA);
      ap.u[6] = bfb(((byte & 64u) ? e1.z * ivA : 0.f) + eaA);
      ap.u[7] = bfb(((byte & 128u) ? e1.w * ivA : 0.f) + eaA);
      acc = __builtin_amdgcn_mfma_f32_16x16x32_bf16(
          ap.v, __builtin_bit_cast(s8v, bfrag[f]), acc, 0, 0, 0);
    }
  }

  // --- epilogue: C/D layout col(lane&15)=e-block idx, row=(lane>>4)*4+reg ---
  {
    float* op = out0 + ((size_t)(b * N_ + n0 + gr * 4)) * (HH * DOUT) +
                h * DOUT + 16 * w + gc;
#pragma unroll
    for (int j = 0; j < 4; ++j) {
      op[(size_t)j * (HH * DOUT)] = fmaxf(acc[j], 0.f);
    }
  }
}

// ---------------------------------------------------------------------------
extern "C" void kernel_launch(void* const* d_in, const int* in_sizes, int n_in,
                              void* d_out, int out_size, void* d_ws,
                              size_t ws_size, hipStream_t stream) {
  const float* H = (const float*)d_in[0];   // (4,2048,256)
  const int* adj = (const int*)d_in[1];     // (4,2048,2048)
  const float* W = (const float*)d_in[2];   // (8,256,64)
  const float* a = (const float*)d_in[3];   // (8,128)

  float* out = (float*)d_out;
  float* out0 = out;                                 // (4,2048,512)
  float* alpha = out + (size_t)B_ * N_ * HH * DOUT;  // (4,8,2048,2048)

  unsigned short* Wht = (unsigned short*)d_ws;        // bf16 [bh][n/32][e][32]
  float* f2 = (float*)(Wht + (size_t)B_ * HH * DOUT * N_);
  float* Ef2 = f2 + (size_t)B_ * HH * N_;
  unsigned long long* bitsG = (unsigned long long*)(Ef2 + (size_t)B_ * HH * N_);
  // bitsG: 512 blocks * 512 u64 = 2 MB

  k_wh_f2<<<B_ * HH * (N_ / 16), 256, 0, stream>>>(H, W, a, Wht, f2);
  k_ef2<<<B_ * HH, 256, 0, stream>>>(f2, Ef2);
  k_pack<<<B_ * (N_ / 16), 256, 0, stream>>>(adj, bitsG);
  k_main<<<B_ * HH * (N_ / 16), 256, 0, stream>>>(bitsG, Ef2, Wht, out0, alpha);
}

// Round 6
// 171.268 us; speedup vs baseline: 13.6835x; 1.1997x over previous
//
#include <hip/hip_runtime.h>

#define B_  4
#define N_  2048
#define DIN 256
#define DOUT 64
#define HH  8
#define CH  256   // m-chunk (register blocking only; no LDS staging)

typedef short s8v __attribute__((ext_vector_type(8)));
typedef float f4v __attribute__((ext_vector_type(4)));

__device__ inline unsigned short bfb(float x) {
  return __builtin_bit_cast(unsigned short, (__bf16)x);
}

// ---------------------------------------------------------------------------
// Kernel 1 (fused): per block (bh, 16-row tile):
//  (a) pack 2 adjacency rows (rows 2h, 2h+1 of the tile) -> bitsG
//  (b) Wh = H @ W, f2 = Wh . a2; Wht layout [bh][seg=n/32][e][32] bf16
// ---------------------------------------------------------------------------
__global__ __launch_bounds__(256) void k_wh_f2(
    const float* __restrict__ H, const float* __restrict__ W,
    const float* __restrict__ a, const int* __restrict__ adj,
    unsigned short* __restrict__ Wht, float* __restrict__ f2,
    unsigned long long* __restrict__ bitsG) {
  __shared__ __align__(16) float hs[16][DIN];    // 16 KB
  __shared__ __align__(16) float ows[DOUT][20];  // 5 KB
  const int t = threadIdx.x, w = t >> 6, lane = t & 63;
  const int q = lane >> 4, g = lane & 15;
  const int bh = blockIdx.x >> 7;
  const int tile = blockIdx.x & 127;
  const int b = bh >> 3, h = bh & 7;
  const int n0 = tile * 16;

  // --- (a) pack two adj rows: row = n0 + 2h + (w>>1), half = w&1 ---
  {
    const int rl = w >> 1, part = w & 1;
    const int nrow = n0 + 2 * h + rl;
    const int* arow = adj + ((size_t)b * N_ + nrow) * N_ + part * 1024;
    int av[16];
#pragma unroll
    for (int i = 0; i < 16; ++i) av[i] = arow[i * 64 + lane];
    unsigned long long* bout =
        bitsG + ((size_t)(b * 128 + tile)) * 512 + (2 * h + rl) * 32 + part * 16;
#pragma unroll
    for (int i = 0; i < 16; ++i) {
      unsigned long long msk = __ballot(av[i] != 0);
      if (lane == 0) bout[i] = msk;
    }
  }

  // --- (b) GEMM tile ---
  const float* Hbase = H + ((size_t)(b * N_ + n0)) * DIN;
#pragma unroll
  for (int j = 0; j < 4; ++j) {
    int idx = j * 256 + t;
    int row = idx >> 6, c4 = idx & 63;
    float4 v = *reinterpret_cast<const float4*>(Hbase + (size_t)row * DIN + c4 * 4);
    *reinterpret_cast<float4*>(&hs[row][c4 * 4]) = v;
  }
  __syncthreads();

  const float* Wp = W + (size_t)h * DIN * DOUT;
  const float4 a2v = *reinterpret_cast<const float4*>(a + h * (2 * DOUT) + DOUT + 4 * g);

  float4 acc[4];
#pragma unroll
  for (int r = 0; r < 4; ++r) acc[r] = make_float4(0.f, 0.f, 0.f, 0.f);

#pragma unroll 4
  for (int d0 = 0; d0 < DIN; d0 += 4) {
    const float4 wv = *reinterpret_cast<const float4*>(Wp + (size_t)(d0 + q) * DOUT + 4 * g);
#pragma unroll
    for (int r = 0; r < 4; ++r) {
      const float hv = hs[w * 4 + r][d0 + q];
      acc[r].x += hv * wv.x; acc[r].y += hv * wv.y;
      acc[r].z += hv * wv.z; acc[r].w += hv * wv.w;
    }
  }

#pragma unroll
  for (int r = 0; r < 4; ++r) {
    float4 v = acc[r];
#pragma unroll
    for (int off = 16; off <= 32; off <<= 1) {
      v.x += __shfl_xor(v.x, off, 64);
      v.y += __shfl_xor(v.y, off, 64);
      v.z += __shfl_xor(v.z, off, 64);
      v.w += __shfl_xor(v.w, off, 64);
    }
    const int n = n0 + w * 4 + r;
    if (q == 0) {
      ows[4 * g + 0][w * 4 + r] = v.x;
      ows[4 * g + 1][w * 4 + r] = v.y;
      ows[4 * g + 2][w * 4 + r] = v.z;
      ows[4 * g + 3][w * 4 + r] = v.w;
    }
    float fr = v.x * a2v.x + v.y * a2v.y + v.z * a2v.z + v.w * a2v.w;
    fr += __shfl_xor(fr, 1, 64);
    fr += __shfl_xor(fr, 2, 64);
    fr += __shfl_xor(fr, 4, 64);
    fr += __shfl_xor(fr, 8, 64);
    if (lane == 0) f2[(size_t)bh * N_ + n] = fr;
  }
  __syncthreads();

  // write tile into [bh][seg][e][32]: seg = tile>>1, half = tile&1
  {
    const int e = t >> 2, quad = t & 3;
    const int seg = tile >> 1, half = tile & 1;
    float4 f = *reinterpret_cast<const float4*>(&ows[e][quad * 4]);
    ushort4 pkv;
    pkv.x = bfb(f.x); pkv.y = bfb(f.y); pkv.z = bfb(f.z); pkv.w = bfb(f.w);
    *reinterpret_cast<ushort4*>(Wht + (size_t)bh * (DOUT * N_) +
                                ((size_t)seg * 64 + e) * 32 + half * 16 + quad * 4) = pkv;
  }
}

// ---------------------------------------------------------------------------
// Kernel 1b: per (b,h): mx = max_m f2; Ef2[m] = exp(f2[m]-mx)
// ---------------------------------------------------------------------------
__global__ __launch_bounds__(256) void k_ef2(const float* __restrict__ f2,
                                             float* __restrict__ Ef2) {
  __shared__ float red[256];
  const int bh = blockIdx.x;
  const int t = threadIdx.x;
  const float* src = f2 + (size_t)bh * N_;
  float v[8];
  float mx = -1e30f;
#pragma unroll
  for (int j = 0; j < 8; ++j) {
    v[j] = src[t + j * 256];
    mx = fmaxf(mx, v[j]);
  }
  red[t] = mx;
  __syncthreads();
  for (int s = 128; s > 0; s >>= 1) {
    if (t < s) red[t] = fmaxf(red[t], red[t + s]);
    __syncthreads();
  }
  mx = red[0];
  float* dst = Ef2 + (size_t)bh * N_;
#pragma unroll
  for (int j = 0; j < 8; ++j) dst[t + j * 256] = __expf(v[j] - mx);
}

// ---------------------------------------------------------------------------
// Kernel 1c: in-place scale Wht[bh][seg][e][m] *= Ef2[bh][seg*32+m]
// grid = 32 bh x 64 seg; 2048 bf16 per block (1024 u32, 4 per thread).
// ---------------------------------------------------------------------------
__global__ __launch_bounds__(256) void k_scale(const float* __restrict__ Ef2,
                                               unsigned short* __restrict__ Wht) {
  __shared__ float efl[32];
  const int t = threadIdx.x;
  const int bh = blockIdx.x >> 6;
  const int seg = blockIdx.x & 63;
  if (t < 8) {
    *reinterpret_cast<float4*>(&efl[t * 4]) =
        *reinterpret_cast<const float4*>(Ef2 + (size_t)bh * N_ + seg * 32 + t * 4);
  }
  __syncthreads();
  unsigned* base = reinterpret_cast<unsigned*>(Wht) + (size_t)bh * 65536 + seg * 1024;
  uint4 v = *reinterpret_cast<uint4*>(base + t * 4);
  unsigned rr[4] = {v.x, v.y, v.z, v.w};
#pragma unroll
  for (int k2 = 0; k2 < 4; ++k2) {
    const int mlo = ((t * 4 + k2) * 2) & 31;
    const unsigned u = rr[k2];
    float lo = __builtin_bit_cast(float, u << 16);
    float hi = __builtin_bit_cast(float, u & 0xFFFF0000u);
    lo *= efl[mlo];
    hi *= efl[mlo + 1];
    rr[k2] = ((unsigned)bfb(lo)) | (((unsigned)bfb(hi)) << 16);
  }
  *reinterpret_cast<uint4*>(base + t * 4) = make_uint4(rr[0], rr[1], rr[2], rr[3]);
}

// ---------------------------------------------------------------------------
// Kernel 2: block = (bh, 16-row tile), 4096 blocks, one head each.
// A = 0/1 bit matrix (bf16), B = ef-scaled Wh; epilogue scales rows by 1/S.
// ---------------------------------------------------------------------------
__global__ __launch_bounds__(256, 4) void k_main(
    const unsigned long long* __restrict__ bitsG, const float* __restrict__ Ef2,
    const unsigned short* __restrict__ WhtG, float* __restrict__ out0,
    float* __restrict__ alpha) {
  __shared__ __align__(16) float ef2s[N_];                   // 8 KB
  __shared__ __align__(16) unsigned long long bits[16][32];  // 4 KB
  __shared__ float ivs[16];
  __shared__ float eas[16];

  const int t = threadIdx.x, w = t >> 6, lane = t & 63;
  const int gr = lane >> 4;   // 0..3
  const int gc = lane & 15;   // 0..15
  const int wg = (blockIdx.x & 7) * 512 + (blockIdx.x >> 3);
  const int bh = wg >> 7;
  const int tile = wg & 127;
  const int b = bh >> 3, h = bh & 7;
  const int n0 = tile * 16;
  const int r = 4 * w + gr;
  const float invN = 1.f / (float)N_;

  reinterpret_cast<uint4*>(&bits[0][0])[t] =
      reinterpret_cast<const uint4*>(bitsG + ((size_t)(b * 128 + tile)) * 512)[t];
  {
    const float4* src = reinterpret_cast<const float4*>(Ef2 + (size_t)bh * N_);
    float4* dst = reinterpret_cast<float4*>(ef2s);
    dst[t] = src[t];
    dst[t + 256] = src[t + 256];
  }
  __syncthreads();

  // --- S-pass ---
  {
    float s0 = 0.f, s1 = 0.f, s2 = 0.f, s3 = 0.f;
#pragma unroll 4
    for (int k = 0; k < 32; ++k) {
      const float ef = ef2s[k * 64 + lane];
      const unsigned long long w0 = bits[4 * w + 0][k];
      const unsigned long long w1 = bits[4 * w + 1][k];
      const unsigned long long w2 = bits[4 * w + 2][k];
      const unsigned long long w3 = bits[4 * w + 3][k];
      s0 += ((w0 >> lane) & 1ull) ? ef : 0.f;
      s1 += ((w1 >> lane) & 1ull) ? ef : 0.f;
      s2 += ((w2 >> lane) & 1ull) ? ef : 0.f;
      s3 += ((w3 >> lane) & 1ull) ? ef : 0.f;
    }
#pragma unroll
    for (int off = 32; off > 0; off >>= 1) {
      s0 += __shfl_xor(s0, off, 64);
      s1 += __shfl_xor(s1, off, 64);
      s2 += __shfl_xor(s2, off, 64);
      s3 += __shfl_xor(s3, off, 64);
    }
    if (lane == 0) {
      float sv[4] = {s0, s1, s2, s3};
#pragma unroll
      for (int rr = 0; rr < 4; ++rr) {
        const bool emp = (sv[rr] == 0.f);
        ivs[4 * w + rr] = emp ? 0.f : 1.f / sv[rr];
        eas[4 * w + rr] = emp ? invN : 0.f;
      }
    }
  }
  __syncthreads();

  const float ivR = ivs[r], eaR = eas[r];
  const unsigned* bitsU = reinterpret_cast<const unsigned*>(&bits[0][0]);  // [16][64]

  const char* WhtB = reinterpret_cast<const char*>(WhtG + (size_t)bh * (DOUT * N_));
  float* alphaRow = alpha + ((size_t)bh * N_ + (size_t)(n0 + r)) * N_;
  f4v acc = {0.f, 0.f, 0.f, 0.f};

  for (int mc = 0; mc < N_; mc += CH) {
    // --- B-fragment loads (ef-scaled Wh), issued first ---
    uint4 bfrag[8];
#pragma unroll
    for (int f = 0; f < 8; ++f) {
      bfrag[f] = *reinterpret_cast<const uint4*>(
          WhtB + (((size_t)((mc >> 5) + f) * 64 + 16 * w + gc) * 32 + gr * 8) * 2);
    }

    // --- alpha: exact f32, coalesced NT stores ---
#pragma unroll
    for (int j4 = 0; j4 < 4; ++j4) {
      const unsigned long long word = bits[r][(mc >> 6) + j4];
      const unsigned nib = (unsigned)(word >> (gc * 4)) & 0xFu;
      const float4 ev = *reinterpret_cast<const float4*>(&ef2s[mc + j4 * 64 + gc * 4]);
      f4v av4;
      av4[0] = ((nib & 1u) ? ev.x * ivR : 0.f) + eaR;
      av4[1] = ((nib & 2u) ? ev.y * ivR : 0.f) + eaR;
      av4[2] = ((nib & 4u) ? ev.z * ivR : 0.f) + eaR;
      av4[3] = ((nib & 8u) ? ev.w * ivR : 0.f) + eaR;
      __builtin_nontemporal_store(
          av4, reinterpret_cast<f4v*>(alphaRow + mc + j4 * 64 + gc * 4));
    }

    // --- MFMA: A = 0/1 bf16 built by bit-spread (row gc, k = f*32+gr*8+j) ---
#pragma unroll
    for (int f = 0; f < 8; ++f) {
      const unsigned u32w = bitsU[gc * 64 + (mc >> 5) + f];
      const unsigned byte = (u32w >> (gr * 8)) & 0xFFu;
      const unsigned lo4 = ((byte & 0xFu) * 0x00204081u) & 0x01010101u;
      const unsigned hi4 = ((byte >> 4) * 0x00204081u) & 0x01010101u;
      union { unsigned u32[4]; s8v v; } ap;
      ap.u32[0] = (unsigned)__mul24((int)__builtin_amdgcn_perm(0u, lo4, 0x0C010C00u), 0x3F80);
      ap.u32[1] = (unsigned)__mul24((int)__builtin_amdgcn_perm(0u, lo4, 0x0C030C02u), 0x3F80);
      ap.u32[2] = (unsigned)__mul24((int)__builtin_amdgcn_perm(0u, hi4, 0x0C010C00u), 0x3F80);
      ap.u32[3] = (unsigned)__mul24((int)__builtin_amdgcn_perm(0u, hi4, 0x0C030C02u), 0x3F80);
      acc = __builtin_amdgcn_mfma_f32_16x16x32_bf16(
          ap.v, __builtin_bit_cast(s8v, bfrag[f]), acc, 0, 0, 0);
    }
  }

  // --- epilogue: scale row (gr*4+j) by iv (or invN fallback), relu, store ---
  bool anyEmp = false;
#pragma unroll
  for (int rr = 0; rr < 16; ++rr) anyEmp |= (eas[rr] != 0.f);

  float* op = out0 + ((size_t)(b * N_ + n0 + gr * 4)) * (HH * DOUT) +
              h * DOUT + 16 * w + gc;
#pragma unroll
  for (int j = 0; j < 4; ++j) {
    const float sc = ivs[gr * 4 + j];
    op[(size_t)j * (HH * DOUT)] = fmaxf(acc[j] * sc, 0.f);
  }

  if (anyEmp) {  // exact uniform-softmax path; statistically never taken
    const unsigned short* WhtU = reinterpret_cast<const unsigned short*>(WhtB);
    for (int j = 0; j < 4; ++j) {
      if (eas[gr * 4 + j] != 0.f) {
        const int e = 16 * w + gc;
        float sum = 0.f;
        for (int m = 0; m < N_; ++m) {
          const unsigned short us = WhtU[((size_t)(m >> 5) * 64 + e) * 32 + (m & 31)];
          const float whe = __builtin_bit_cast(float, (unsigned)us << 16);
          sum += whe / ef2s[m];
        }
        op[(size_t)j * (HH * DOUT)] = fmaxf(sum * invN, 0.f);
      }
    }
  }
}

// ---------------------------------------------------------------------------
extern "C" void kernel_launch(void* const* d_in, const int* in_sizes, int n_in,
                              void* d_out, int out_size, void* d_ws,
                              size_t ws_size, hipStream_t stream) {
  const float* H = (const float*)d_in[0];   // (4,2048,256)
  const int* adj = (const int*)d_in[1];     // (4,2048,2048)
  const float* W = (const float*)d_in[2];   // (8,256,64)
  const float* a = (const float*)d_in[3];   // (8,128)

  float* out = (float*)d_out;
  float* out0 = out;                                 // (4,2048,512)
  float* alpha = out + (size_t)B_ * N_ * HH * DOUT;  // (4,8,2048,2048)

  unsigned short* Wht = (unsigned short*)d_ws;        // bf16 [bh][n/32][e][32]
  float* f2 = (float*)(Wht + (size_t)B_ * HH * DOUT * N_);
  float* Ef2 = f2 + (size_t)B_ * HH * N_;
  unsigned long long* bitsG = (unsigned long long*)(Ef2 + (size_t)B_ * HH * N_);

  k_wh_f2<<<B_ * HH * (N_ / 16), 256, 0, stream>>>(H, W, a, adj, Wht, f2, bitsG);
  k_ef2<<<B_ * HH, 256, 0, stream>>>(f2, Ef2);
  k_scale<<<B_ * HH * (N_ / 32), 256, 0, stream>>>(Ef2, Wht);
  k_main<<<B_ * HH * (N_ / 16), 256, 0, stream>>>(bitsG, Ef2, Wht, out0, alpha);
}